// Round 6
// baseline (363.059 us; speedup 1.0000x reference)
//
#include <hip/hip_runtime.h>
#include <math.h>
#include <stdint.h>

#define TSEQ 2048
#define NB   4
#define CD   1024
#define NH   16
#define HD   64
#define MR   8192   // NB*TSEQ

typedef __bf16 bf16x8 __attribute__((ext_vector_type(8)));
typedef float  f32x4  __attribute__((ext_vector_type(4)));
typedef float  f32x16 __attribute__((ext_vector_type(16)));

// fp32 -> bf16 round-to-nearest-even
__device__ __forceinline__ unsigned short f2b(float f) {
  unsigned u = __float_as_uint(f);
  u += 0x7fffu + ((u >> 16) & 1u);
  return (unsigned short)(u >> 16);
}
__device__ __forceinline__ unsigned cvtpk(float lo, float hi) {
  unsigned r;
  asm("v_cvt_pk_bf16_f32 %0, %1, %2" : "=v"(r) : "v"(lo), "v"(hi));
  return r;
}

// async global->LDS, 16B per lane: LDS dest = wave-uniform base + lane*16.
__device__ __forceinline__ void gll16(const void* g, const void* l) {
  __builtin_amdgcn_global_load_lds(
      (const __attribute__((address_space(1))) unsigned*)(uintptr_t)g,
      (__attribute__((address_space(3))) unsigned*)(uintptr_t)l, 16, 0, 0);
}

// ---------------- cast x (8192x1024 f32 -> bf16, same layout) ----------------
__global__ __launch_bounds__(256) void cast_x_k(const float* __restrict__ in,
                                                unsigned short* __restrict__ out) {
  int i = blockIdx.x * 256 + threadIdx.x;
  const float4* p = (const float4*)in;
  float4 a = p[2 * i], b = p[2 * i + 1];
  uint4 o;
  o.x = f2b(a.x) | ((unsigned)f2b(a.y) << 16);
  o.y = f2b(a.z) | ((unsigned)f2b(a.w) << 16);
  o.z = f2b(b.x) | ((unsigned)f2b(b.y) << 16);
  o.w = f2b(b.z) | ((unsigned)f2b(b.w) << 16);
  ((uint4*)out)[i] = o;
}

// ------------- cast + transpose weights: (K,N) f32 -> (N,K) bf16 -------------
__global__ __launch_bounds__(256) void castT_k(
    const float* __restrict__ w0, const float* __restrict__ w1,
    const float* __restrict__ w2, const float* __restrict__ w3,
    unsigned short* __restrict__ o0, unsigned short* __restrict__ o1,
    unsigned short* __restrict__ o2, unsigned short* __restrict__ o3) {
  const float* W = blockIdx.z == 0 ? w0 : blockIdx.z == 1 ? w1 : blockIdx.z == 2 ? w2 : w3;
  unsigned short* O = blockIdx.z == 0 ? o0 : blockIdx.z == 1 ? o1 : blockIdx.z == 2 ? o2 : o3;
  __shared__ float t[32][33];
  int tx = threadIdx.x & 31, ty = threadIdx.x >> 5;
  #pragma unroll
  for (int i = 0; i < 4; ++i)
    t[ty + i * 8][tx] = W[(size_t)(blockIdx.y * 32 + ty + i * 8) * CD + blockIdx.x * 32 + tx];
  __syncthreads();
  #pragma unroll
  for (int i = 0; i < 4; ++i)
    O[(size_t)(blockIdx.x * 32 + ty + i * 8) * CD + blockIdx.y * 32 + tx] = f2b(t[tx][ty + i * 8]);
}

// ---------------- bf16 GEMM: C = A(M,K) @ Bt(N,K)^T -------------------------
// 128x128 tile, BK=32, 4 waves 2x2, T3 2-phase dbuf prefetch.
// MODE 3: fused QKV (N=3072): Q natural, K natural, V -> (B,H,D,T).
// MODE 2: f32 out + bias.
template <int MODE>
__global__ __launch_bounds__(256) void gemm_k(const unsigned short* __restrict__ A,
                                              const unsigned short* __restrict__ Bt,
                                              void* __restrict__ o0, void* __restrict__ o1,
                                              void* __restrict__ o2,
                                              const float* __restrict__ bias) {
  __shared__ __align__(16) unsigned short Asl[2][128 * 32];  // 8 KB each
  __shared__ __align__(16) unsigned short Bsl[2][128 * 32];
  const int tid = threadIdx.x, lane = tid & 63, w = tid >> 6;
  const int li = lane & 15, lg = lane >> 4;
  // bijective XCD swizzle: chunk per XCD, bm fastest (B-panel L2 reuse)
  const int nwg = gridDim.x * gridDim.y;                 // 1536 or 512 (%8==0)
  const int bid = blockIdx.y * gridDim.x + blockIdx.x;
  const int swz = (bid & 7) * (nwg >> 3) + (bid >> 3);
  const int bm = swz & 63, bn = swz >> 6;
  const int wr = w >> 1, wc = w & 1;

  f32x4 acc[4][4];
  #pragma unroll
  for (int mi = 0; mi < 4; ++mi)
    #pragma unroll
    for (int ni = 0; ni < 4; ++ni) acc[mi][ni] = (f32x4){0.f, 0.f, 0.f, 0.f};

  auto stage = [&](int kt, int buf) {
    #pragma unroll
    for (int it = 0; it < 2; ++it) {
      int c = (w * 2 + it) * 64 + lane;
      int r = c >> 2, ko = (c & 3) * 8;
      gll16(A  + (size_t)(bm * 128 + r) * CD + kt * 32 + ko,
            (const char*)Asl[buf] + (w * 2 + it) * 1024);
      gll16(Bt + (size_t)(bn * 128 + r) * CD + kt * 32 + ko,
            (const char*)Bsl[buf] + (w * 2 + it) * 1024);
    }
  };

  stage(0, 0);
  __syncthreads();                       // tile 0 resident (vmcnt drain + barrier)

  #pragma unroll 2
  for (int kt = 0; kt < 32; ++kt) {
    const int buf = kt & 1;
    if (kt + 1 < 32) stage(kt + 1, buf ^ 1);   // prefetch overlaps compute below
    bf16x8 af[4], bfr[4];
    #pragma unroll
    for (int mi = 0; mi < 4; ++mi)
      af[mi] = *(const bf16x8*)&Asl[buf][(wr * 64 + mi * 16 + li) * 32 + lg * 8];
    #pragma unroll
    for (int ni = 0; ni < 4; ++ni)
      bfr[ni] = *(const bf16x8*)&Bsl[buf][(wc * 64 + ni * 16 + li) * 32 + lg * 8];
    #pragma unroll
    for (int mi = 0; mi < 4; ++mi)
      #pragma unroll
      for (int ni = 0; ni < 4; ++ni)
        acc[mi][ni] = __builtin_amdgcn_mfma_f32_16x16x32_bf16(af[mi], bfr[ni], acc[mi][ni], 0, 0, 0);
    __syncthreads();                     // drains prefetch vmcnt + lgkm + barrier
  }

  // C/D layout: col=lane&15, row=(lane>>4)*4+reg
  #pragma unroll
  for (int mi = 0; mi < 4; ++mi)
    #pragma unroll
    for (int ni = 0; ni < 4; ++ni)
      #pragma unroll
      for (int r = 0; r < 4; ++r) {
        int row = bm * 128 + wr * 64 + mi * 16 + lg * 4 + r;
        int col = bn * 128 + wc * 64 + ni * 16 + li;
        float v = acc[mi][ni][r];
        if constexpr (MODE == 3) {
          int seg = col >> 10, c2 = col & 1023;
          if (seg == 0) {
            ((unsigned short*)o0)[(size_t)row * CD + c2] = f2b(v);
          } else if (seg == 1) {
            ((unsigned short*)o1)[(size_t)row * CD + c2] = f2b(v);
          } else {
            int b = row >> 11, t = row & 2047;
            ((unsigned short*)o2)[(size_t)(b * CD + c2) * TSEQ + t] = f2b(v);
          }
        } else {
          ((float*)o0)[(size_t)row * CD + col] = v + bias[col];
        }
      }
}

// ---------------- bf16 MFMA flash attention (causal), 32x32x16 ---------------
// 1024 blocks (4/CU), 4 waves each; wave owns 32 q-rows, q-tile = 128 rows.
// Heavy tiles dispatched first (qt = 15-qi); XCD-chunked swizzle keeps one
// (b,h)'s blocks on one XCD (K/V 512 KB -> L2 resident).
// QK^T swapped: mfma(A=K,B=Q) -> lane owns q=lane&31, 16 k-vals.
// PV as O^T = mfma(A=V^T, B=P^T): P^T frag = own p + shfl_xor(32) partner.
// Defer-max (T13): skip O-rescale when max growth <= 8 (log2 units).
__global__ __launch_bounds__(256) void attn_k(const unsigned short* __restrict__ Qm,
                                              const unsigned short* __restrict__ Km,
                                              const unsigned short* __restrict__ Vt,
                                              unsigned short* __restrict__ Cx) {
  __shared__ __align__(16) unsigned short Kt[2][2048];  // 4 frags * 64 lanes * 16B
  __shared__ __align__(16) unsigned short Vs[2][2048];
  const int tid = threadIdx.x, w = tid >> 6, lane = tid & 63;
  const int q32 = lane & 31, hi = lane >> 5;
  const int bid = blockIdx.x;                     // 0..1023
  const int swz = (bid & 7) * 128 + (bid >> 3);   // XCD-chunked
  const int bh = swz >> 4, qi = swz & 15;
  const int qt = 15 - qi;                         // heavy first within chunk
  const int b = bh >> 4, h = bh & 15;
  const float SC = 0.18033688011112042f;          // log2(e)/sqrt(64)

  const int qloc = qt * 128 + w * 32 + q32;
  const size_t qrow = (size_t)(b * TSEQ) + qloc;
  const int NKB = qt * 4 + 4;
  const int diag = qt * 4 + w;

  bf16x8 qf[4];
  #pragma unroll
  for (int dc = 0; dc < 4; ++dc)
    qf[dc] = *(const bf16x8*)&Qm[qrow * CD + h * 64 + dc * 16 + hi * 8];

  f32x16 oc0, oc1;
  #pragma unroll
  for (int r = 0; r < 16; ++r) { oc0[r] = 0.f; oc1[r] = 0.f; }
  float m = -INFINITY, lsum = 0.f;

  // wave w stages K-frag dc=w and V-frag (kchunk=w>>1, dhalf=w&1)
  auto stage = [&](int kb, int buf) {
    gll16(Km + (size_t)(b * TSEQ + kb * 32 + q32) * CD + h * 64 + w * 16 + hi * 8,
          (const char*)&Kt[buf][w * 512]);
    gll16(Vt + ((size_t)b * CD + h * 64 + (w & 1) * 32 + q32) * TSEQ + kb * 32 + (w >> 1) * 16 + hi * 8,
          (const char*)&Vs[buf][w * 512]);
  };

  stage(0, 0);
  #pragma unroll 1
  for (int kb = 0; kb < NKB; ++kb) {
    const int buf = kb & 1;
    if (kb + 1 < NKB) {
      stage(kb + 1, buf ^ 1);
      asm volatile("s_waitcnt vmcnt(2)" ::: "memory");
    } else {
      asm volatile("s_waitcnt vmcnt(0)" ::: "memory");
    }
    __builtin_amdgcn_s_barrier();
    __builtin_amdgcn_sched_barrier(0);

    // S^T = K @ Q^T over d=64 (4 x K=16)
    f32x16 st;
    #pragma unroll
    for (int r = 0; r < 16; ++r) st[r] = 0.f;
    #pragma unroll
    for (int dc = 0; dc < 4; ++dc) {
      bf16x8 kf = *(const bf16x8*)&Kt[buf][dc * 512 + lane * 8];
      st = __builtin_amdgcn_mfma_f32_32x32x16_bf16(kf, qf[dc], st, 0, 0, 0);
    }

    if (kb >= diag) {  // causal mask on the diagonal tile
      #pragma unroll
      for (int r = 0; r < 16; ++r) {
        int kloc = kb * 32 + (r & 3) + 8 * (r >> 2) + 4 * hi;
        if (kloc > qloc) st[r] = -INFINITY;
      }
    }

    // row max (tree), pair lanes l,l+32 share q
    float m01 = fmaxf(st[0], st[1]),  m23 = fmaxf(st[2], st[3]);
    float m45 = fmaxf(st[4], st[5]),  m67 = fmaxf(st[6], st[7]);
    float m89 = fmaxf(st[8], st[9]),  mab = fmaxf(st[10], st[11]);
    float mcd = fmaxf(st[12], st[13]), mef = fmaxf(st[14], st[15]);
    float rmax = fmaxf(fmaxf(fmaxf(m01, m23), fmaxf(m45, m67)),
                       fmaxf(fmaxf(m89, mab), fmaxf(mcd, mef)));
    rmax = fmaxf(rmax, __shfl_xor(rmax, 32));

    // defer-max: only rescale when growth exceeds 2^8
    if (!__all((rmax - m) * SC <= 8.f)) {
      float mnew = fmaxf(m, rmax);
      float alpha = exp2f((m - mnew) * SC);
      lsum *= alpha;
      #pragma unroll
      for (int r = 0; r < 16; ++r) { oc0[r] *= alpha; oc1[r] *= alpha; }
      m = mnew;
    }

    float p[16], psum = 0.f;
    #pragma unroll
    for (int r = 0; r < 16; ++r) {
      p[r] = exp2f((st[r] - m) * SC);
      psum += p[r];
    }
    psum += __shfl_xor(psum, 32);
    lsum += psum;

    // pack P -> bf16 pairs; W[s][t] covers k = 8s + 4hi + 2t + {0,1}
    unsigned W[4][2], X[4][2];
    #pragma unroll
    for (int s = 0; s < 4; ++s)
      #pragma unroll
      for (int t = 0; t < 2; ++t) W[s][t] = cvtpk(p[4 * s + 2 * t], p[4 * s + 2 * t + 1]);
    #pragma unroll
    for (int s = 0; s < 4; ++s)
      #pragma unroll
      for (int t = 0; t < 2; ++t) X[s][t] = __shfl_xor(W[s][t], 32);

    const bool h1 = (hi == 1);
    uint4 pw0, pw1;  // B-frag chunk c: k = 16c + 8*hi + {0..7}
    pw0.x = h1 ? X[1][0] : W[0][0];
    pw0.y = h1 ? X[1][1] : W[0][1];
    pw0.z = h1 ? W[1][0] : X[0][0];
    pw0.w = h1 ? W[1][1] : X[0][1];
    pw1.x = h1 ? X[3][0] : W[2][0];
    pw1.y = h1 ? X[3][1] : W[2][1];
    pw1.z = h1 ? W[3][0] : X[2][0];
    pw1.w = h1 ? W[3][1] : X[2][1];
    bf16x8 pb0 = *(bf16x8*)&pw0, pb1 = *(bf16x8*)&pw1;

    // O^T += V^T @ P^T : 2 k-chunks x 2 d-halves
    {
      bf16x8 v00 = *(const bf16x8*)&Vs[buf][(0 * 2 + 0) * 512 + lane * 8];
      bf16x8 v01 = *(const bf16x8*)&Vs[buf][(0 * 2 + 1) * 512 + lane * 8];
      bf16x8 v10 = *(const bf16x8*)&Vs[buf][(1 * 2 + 0) * 512 + lane * 8];
      bf16x8 v11 = *(const bf16x8*)&Vs[buf][(1 * 2 + 1) * 512 + lane * 8];
      oc0 = __builtin_amdgcn_mfma_f32_32x32x16_bf16(v00, pb0, oc0, 0, 0, 0);
      oc1 = __builtin_amdgcn_mfma_f32_32x32x16_bf16(v01, pb0, oc1, 0, 0, 0);
      oc0 = __builtin_amdgcn_mfma_f32_32x32x16_bf16(v10, pb1, oc0, 0, 0, 0);
      oc1 = __builtin_amdgcn_mfma_f32_32x32x16_bf16(v11, pb1, oc1, 0, 0, 0);
    }
    asm volatile("s_waitcnt lgkmcnt(0)" ::: "memory");
    __builtin_amdgcn_s_barrier();
  }

  // epilogue: lane owns q = qloc; o-reg r -> d = (r&3) + 8*(r>>2) + 4*hi (+32 for oc1)
  float inv = 1.f / lsum;
  #pragma unroll
  for (int dh = 0; dh < 2; ++dh)
    #pragma unroll
    for (int g = 0; g < 4; ++g) {
      ushort4 sv;
      float v0 = (dh ? oc1[4 * g + 0] : oc0[4 * g + 0]) * inv;
      float v1 = (dh ? oc1[4 * g + 1] : oc0[4 * g + 1]) * inv;
      float v2 = (dh ? oc1[4 * g + 2] : oc0[4 * g + 2]) * inv;
      float v3 = (dh ? oc1[4 * g + 3] : oc0[4 * g + 3]) * inv;
      sv.x = f2b(v0); sv.y = f2b(v1); sv.z = f2b(v2); sv.w = f2b(v3);
      *(ushort4*)&Cx[qrow * CD + h * 64 + dh * 32 + 8 * g + 4 * hi] = sv;
    }
}

// ---------------- launch ----------------
extern "C" void kernel_launch(void* const* d_in, const int* in_sizes, int n_in,
                              void* d_out, int out_size, void* d_ws, size_t ws_size,
                              hipStream_t stream) {
  const float* x  = (const float*)d_in[0];
  const float* Wq = (const float*)d_in[1];
  const float* Wk = (const float*)d_in[2];
  const float* Wv = (const float*)d_in[3];
  const float* Wo = (const float*)d_in[4];
  const float* bo = (const float*)d_in[5];
  float* out = (float*)d_out;

  char* W = (char*)d_ws;
  unsigned short* xb  = (unsigned short*)(W);                 // 16 MB
  unsigned short* WqT = (unsigned short*)(W + (16u << 20));   // 2 MB (contig with Wk,Wv)
  unsigned short* WkT = (unsigned short*)(W + (18u << 20));
  unsigned short* WvT = (unsigned short*)(W + (20u << 20));
  unsigned short* WoT = (unsigned short*)(W + (22u << 20));
  unsigned short* Qm  = (unsigned short*)(W + (24u << 20));   // (B,T,C)
  unsigned short* Km  = (unsigned short*)(W + (40u << 20));   // (B,T,C)
  unsigned short* Vt  = (unsigned short*)(W + (56u << 20));   // (B,H,D,T)
  unsigned short* Cx  = (unsigned short*)(W + (72u << 20));   // (B,T,C)

  hipLaunchKernelGGL(cast_x_k, dim3(4096), dim3(256), 0, stream, x, xb);
  hipLaunchKernelGGL(castT_k, dim3(32, 32, 4), dim3(256), 0, stream,
                     Wq, Wk, Wv, Wo, WqT, WkT, WvT, WoT);
  // fused QKV projection: Bt = [WqT;WkT;WvT] rows 0..3071
  hipLaunchKernelGGL((gemm_k<3>), dim3(64, 24), dim3(256), 0, stream,
                     xb, WqT, (void*)Qm, (void*)Km, (void*)Vt, (const float*)nullptr);
  hipLaunchKernelGGL(attn_k, dim3(1024), dim3(256), 0, stream, Qm, Km, Vt, Cx);
  hipLaunchKernelGGL((gemm_k<2>), dim3(64, 8), dim3(256), 0, stream,
                     Cx, WoT, (void*)out, nullptr, nullptr, bo);
}

// Round 7
// 329.832 us; speedup vs baseline: 1.1007x; 1.1007x over previous
//
#include <hip/hip_runtime.h>
#include <math.h>
#include <stdint.h>

#define TSEQ 2048
#define NB   4
#define CD   1024
#define NH   16
#define HD   64
#define MR   8192   // NB*TSEQ

typedef __bf16 bf16x8 __attribute__((ext_vector_type(8)));
typedef float  f32x4  __attribute__((ext_vector_type(4)));
typedef float  f32x16 __attribute__((ext_vector_type(16)));

// fp32 -> bf16 round-to-nearest-even
__device__ __forceinline__ unsigned short f2b(float f) {
  unsigned u = __float_as_uint(f);
  u += 0x7fffu + ((u >> 16) & 1u);
  return (unsigned short)(u >> 16);
}
__device__ __forceinline__ unsigned cvtpk(float lo, float hi) {
  unsigned r;
  asm("v_cvt_pk_bf16_f32 %0, %1, %2" : "=v"(r) : "v"(lo), "v"(hi));
  return r;
}

// async global->LDS, 16B per lane: LDS dest = wave-uniform base + lane*16.
__device__ __forceinline__ void gll16(const void* g, const void* l) {
  __builtin_amdgcn_global_load_lds(
      (const __attribute__((address_space(1))) unsigned*)(uintptr_t)g,
      (__attribute__((address_space(3))) unsigned*)(uintptr_t)l, 16, 0, 0);
}

// ---------------- cast x (8192x1024 f32 -> bf16, same layout) ----------------
__global__ __launch_bounds__(256) void cast_x_k(const float* __restrict__ in,
                                                unsigned short* __restrict__ out) {
  int i = blockIdx.x * 256 + threadIdx.x;
  const float4* p = (const float4*)in;
  float4 a = p[2 * i], b = p[2 * i + 1];
  uint4 o;
  o.x = f2b(a.x) | ((unsigned)f2b(a.y) << 16);
  o.y = f2b(a.z) | ((unsigned)f2b(a.w) << 16);
  o.z = f2b(b.x) | ((unsigned)f2b(b.y) << 16);
  o.w = f2b(b.z) | ((unsigned)f2b(b.w) << 16);
  ((uint4*)out)[i] = o;
}

// ------------- cast + transpose weights: (K,N) f32 -> (N,K) bf16 -------------
__global__ __launch_bounds__(256) void castT_k(
    const float* __restrict__ w0, const float* __restrict__ w1,
    const float* __restrict__ w2, const float* __restrict__ w3,
    unsigned short* __restrict__ o0, unsigned short* __restrict__ o1,
    unsigned short* __restrict__ o2, unsigned short* __restrict__ o3) {
  const float* W = blockIdx.z == 0 ? w0 : blockIdx.z == 1 ? w1 : blockIdx.z == 2 ? w2 : w3;
  unsigned short* O = blockIdx.z == 0 ? o0 : blockIdx.z == 1 ? o1 : blockIdx.z == 2 ? o2 : o3;
  __shared__ float t[32][33];
  int tx = threadIdx.x & 31, ty = threadIdx.x >> 5;
  #pragma unroll
  for (int i = 0; i < 4; ++i)
    t[ty + i * 8][tx] = W[(size_t)(blockIdx.y * 32 + ty + i * 8) * CD + blockIdx.x * 32 + tx];
  __syncthreads();
  #pragma unroll
  for (int i = 0; i < 4; ++i)
    O[(size_t)(blockIdx.x * 32 + ty + i * 8) * CD + blockIdx.y * 32 + tx] = f2b(t[tx][ty + i * 8]);
}

// ---------------- bf16 GEMM (r2-exact, known good) ---------------------------
// 128x128 tile, BK=32, 4 waves 2x2. MODE 3: fused QKV (N=3072): Q natural,
// K natural, V -> (B,H,D,T). MODE 2: f32 out + bias.
template <int MODE>
__global__ __launch_bounds__(256) void gemm_k(const unsigned short* __restrict__ A,
                                              const unsigned short* __restrict__ Bt,
                                              void* __restrict__ o0, void* __restrict__ o1,
                                              void* __restrict__ o2,
                                              const float* __restrict__ bias) {
  __shared__ __align__(16) unsigned short Asl[128 * 32];
  __shared__ __align__(16) unsigned short Bsl[128 * 32];
  const int tid = threadIdx.x, lane = tid & 63, w = tid >> 6;
  const int li = lane & 15, lg = lane >> 4;
  const int bm = blockIdx.x, bn = blockIdx.y;
  const int wr = w >> 1, wc = w & 1;

  f32x4 acc[4][4];
  #pragma unroll
  for (int mi = 0; mi < 4; ++mi)
    #pragma unroll
    for (int ni = 0; ni < 4; ++ni) acc[mi][ni] = (f32x4){0.f, 0.f, 0.f, 0.f};

  for (int kt = 0; kt < 32; ++kt) {
    #pragma unroll
    for (int it = 0; it < 2; ++it) {
      int c = (w * 2 + it) * 64 + lane;
      int r = c >> 2, ko = (c & 3) * 8;
      gll16(A  + (size_t)(bm * 128 + r) * CD + kt * 32 + ko, (const char*)Asl + (w * 2 + it) * 1024);
      gll16(Bt + (size_t)(bn * 128 + r) * CD + kt * 32 + ko, (const char*)Bsl + (w * 2 + it) * 1024);
    }
    __syncthreads();
    bf16x8 af[4], bfr[4];
    #pragma unroll
    for (int mi = 0; mi < 4; ++mi)
      af[mi] = *(const bf16x8*)&Asl[(wr * 64 + mi * 16 + li) * 32 + lg * 8];
    #pragma unroll
    for (int ni = 0; ni < 4; ++ni)
      bfr[ni] = *(const bf16x8*)&Bsl[(wc * 64 + ni * 16 + li) * 32 + lg * 8];
    #pragma unroll
    for (int mi = 0; mi < 4; ++mi)
      #pragma unroll
      for (int ni = 0; ni < 4; ++ni)
        acc[mi][ni] = __builtin_amdgcn_mfma_f32_16x16x32_bf16(af[mi], bfr[ni], acc[mi][ni], 0, 0, 0);
    __syncthreads();
  }

  // C/D layout: col=lane&15, row=(lane>>4)*4+reg
  #pragma unroll
  for (int mi = 0; mi < 4; ++mi)
    #pragma unroll
    for (int ni = 0; ni < 4; ++ni)
      #pragma unroll
      for (int r = 0; r < 4; ++r) {
        int row = bm * 128 + wr * 64 + mi * 16 + lg * 4 + r;
        int col = bn * 128 + wc * 64 + ni * 16 + li;
        float v = acc[mi][ni][r];
        if constexpr (MODE == 3) {
          int seg = col >> 10, c2 = col & 1023;
          if (seg == 0) {
            ((unsigned short*)o0)[(size_t)row * CD + c2] = f2b(v);
          } else if (seg == 1) {
            ((unsigned short*)o1)[(size_t)row * CD + c2] = f2b(v);
          } else {
            int b = row >> 11, t = row & 2047;
            ((unsigned short*)o2)[(size_t)(b * CD + c2) * TSEQ + t] = f2b(v);
          }
        } else {
          ((float*)o0)[(size_t)row * CD + col] = v + bias[col];
        }
      }
}

// ---------------- bf16 MFMA flash attention (causal), 32x32x16 ---------------
// 512 blocks (XCD-chunked), 4 INDEPENDENT waves per block (no s_barrier).
// Wave owns 32 q-rows; block covers q-tiles {pj, 15-pj} (uniform 62+2w units).
// Each wave stages K/V into its PRIVATE LDS region (8 gll16/unit, dbuf,
// per-wave vmcnt(8) counting). Wave stops at its own diagonal.
// QK^T swapped: mfma(A=K,B=Q) -> lane owns q=lane&31, 16 k-vals.
// PV as O^T = mfma(A=V^T, B=P^T): P^T frag = own p + shfl_xor(32) partner.
// Defer-max (T13): skip O-rescale when max growth <= 8 (log2 units).
__global__ __launch_bounds__(256) void attn_k(const unsigned short* __restrict__ Qm,
                                              const unsigned short* __restrict__ Km,
                                              const unsigned short* __restrict__ Vt,
                                              unsigned short* __restrict__ Cx) {
  // [wave][buf][frag 0..7][64 lanes * 16B]; frags 0-3 = K(dc), 4-7 = V(kc*2+dh)
  __shared__ __align__(16) unsigned short L[4][2][8][512];  // 64 KB
  const int tid = threadIdx.x, w = tid >> 6, lane = tid & 63;
  const int q32 = lane & 31, hi = lane >> 5;
  const int bid = blockIdx.x;                    // 0..511
  const int bh = (bid & 7) * 8 + (bid >> 6);     // XCD-chunked: 8 bh per XCD
  const int pj = (bid >> 3) & 7;
  const int b = bh >> 4, h = bh & 15;
  const float SC = 0.18033688011112042f;         // log2(e)/sqrt(64)

  #pragma unroll 1
  for (int pass = 0; pass < 2; ++pass) {
    const int qt = pass ? (15 - pj) : pj;
    const int qloc = qt * 128 + w * 32 + q32;
    const size_t qrow = (size_t)(b * TSEQ) + qloc;
    const int diag = qt * 4 + w;
    const int NKB = diag + 1;                    // stop after own diagonal

    bf16x8 qf[4];
    #pragma unroll
    for (int dc = 0; dc < 4; ++dc)
      qf[dc] = *(const bf16x8*)&Qm[qrow * CD + h * 64 + dc * 16 + hi * 8];

    f32x16 oc0, oc1;
    #pragma unroll
    for (int r = 0; r < 16; ++r) { oc0[r] = 0.f; oc1[r] = 0.f; }
    float m = -INFINITY, lsum = 0.f;

    // wave-private staging: all 8 frags of tile kb into L[w][buf]
    auto stage = [&](int kb, int buf) {
      const char* base = (const char*)&L[w][buf][0][0];
      #pragma unroll
      for (int dc = 0; dc < 4; ++dc)
        gll16(Km + (size_t)(b * TSEQ + kb * 32 + q32) * CD + h * 64 + dc * 16 + hi * 8,
              base + dc * 1024);
      #pragma unroll
      for (int f = 0; f < 4; ++f)   // f = kc*2 + dh
        gll16(Vt + ((size_t)b * CD + h * 64 + (f & 1) * 32 + q32) * TSEQ + kb * 32 + (f >> 1) * 16 + hi * 8,
              base + (4 + f) * 1024);
    };

    stage(0, 0);
    #pragma unroll 1
    for (int kb = 0; kb < NKB; ++kb) {
      const int buf = kb & 1;
      if (kb + 1 < NKB) {
        stage(kb + 1, buf ^ 1);
        asm volatile("s_waitcnt vmcnt(8)" ::: "memory");  // tile kb landed, prefetch in flight
      } else {
        asm volatile("s_waitcnt vmcnt(0)" ::: "memory");
      }

      // S^T = K @ Q^T over d=64 (4 x K=16)
      f32x16 st;
      #pragma unroll
      for (int r = 0; r < 16; ++r) st[r] = 0.f;
      #pragma unroll
      for (int dc = 0; dc < 4; ++dc) {
        bf16x8 kf = *(const bf16x8*)&L[w][buf][dc][lane * 8];
        st = __builtin_amdgcn_mfma_f32_32x32x16_bf16(kf, qf[dc], st, 0, 0, 0);
      }

      if (kb == diag) {  // causal mask on the diagonal tile
        #pragma unroll
        for (int r = 0; r < 16; ++r) {
          int kloc = kb * 32 + (r & 3) + 8 * (r >> 2) + 4 * hi;
          if (kloc > qloc) st[r] = -INFINITY;
        }
      }

      // row max (tree), pair lanes l,l+32 share q
      float m01 = fmaxf(st[0], st[1]),  m23 = fmaxf(st[2], st[3]);
      float m45 = fmaxf(st[4], st[5]),  m67 = fmaxf(st[6], st[7]);
      float m89 = fmaxf(st[8], st[9]),  mab = fmaxf(st[10], st[11]);
      float mcd = fmaxf(st[12], st[13]), mef = fmaxf(st[14], st[15]);
      float rmax = fmaxf(fmaxf(fmaxf(m01, m23), fmaxf(m45, m67)),
                         fmaxf(fmaxf(m89, mab), fmaxf(mcd, mef)));
      rmax = fmaxf(rmax, __shfl_xor(rmax, 32));

      // defer-max: only rescale when growth exceeds 2^8
      if (!__all((rmax - m) * SC <= 8.f)) {
        float mnew = fmaxf(m, rmax);
        float alpha = exp2f((m - mnew) * SC);
        lsum *= alpha;
        #pragma unroll
        for (int r = 0; r < 16; ++r) { oc0[r] *= alpha; oc1[r] *= alpha; }
        m = mnew;
      }

      float p[16], psum = 0.f;
      #pragma unroll
      for (int r = 0; r < 16; ++r) {
        p[r] = exp2f((st[r] - m) * SC);
        psum += p[r];
      }
      psum += __shfl_xor(psum, 32);
      lsum += psum;

      // pack P -> bf16 pairs; W[s][t] covers k = 8s + 4hi + 2t + {0,1}
      unsigned W[4][2], X[4][2];
      #pragma unroll
      for (int s = 0; s < 4; ++s)
        #pragma unroll
        for (int t = 0; t < 2; ++t) W[s][t] = cvtpk(p[4 * s + 2 * t], p[4 * s + 2 * t + 1]);
      #pragma unroll
      for (int s = 0; s < 4; ++s)
        #pragma unroll
        for (int t = 0; t < 2; ++t) X[s][t] = __shfl_xor(W[s][t], 32);

      const bool h1 = (hi == 1);
      uint4 pw0, pw1;  // B-frag chunk c: k = 16c + 8*hi + {0..7}
      pw0.x = h1 ? X[1][0] : W[0][0];
      pw0.y = h1 ? X[1][1] : W[0][1];
      pw0.z = h1 ? W[1][0] : X[0][0];
      pw0.w = h1 ? W[1][1] : X[0][1];
      pw1.x = h1 ? X[3][0] : W[2][0];
      pw1.y = h1 ? X[3][1] : W[2][1];
      pw1.z = h1 ? W[3][0] : X[2][0];
      pw1.w = h1 ? W[3][1] : X[2][1];
      bf16x8 pb0 = *(bf16x8*)&pw0, pb1 = *(bf16x8*)&pw1;

      // O^T += V^T @ P^T : 2 k-chunks x 2 d-halves
      {
        bf16x8 v00 = *(const bf16x8*)&L[w][buf][4 + 0][lane * 8];
        bf16x8 v01 = *(const bf16x8*)&L[w][buf][4 + 1][lane * 8];
        bf16x8 v10 = *(const bf16x8*)&L[w][buf][4 + 2][lane * 8];
        bf16x8 v11 = *(const bf16x8*)&L[w][buf][4 + 3][lane * 8];
        oc0 = __builtin_amdgcn_mfma_f32_32x32x16_bf16(v00, pb0, oc0, 0, 0, 0);
        oc1 = __builtin_amdgcn_mfma_f32_32x32x16_bf16(v01, pb0, oc1, 0, 0, 0);
        oc0 = __builtin_amdgcn_mfma_f32_32x32x16_bf16(v10, pb1, oc0, 0, 0, 0);
        oc1 = __builtin_amdgcn_mfma_f32_32x32x16_bf16(v11, pb1, oc1, 0, 0, 0);
      }
    }

    // epilogue: lane owns q = qloc; o-reg r -> d = (r&3) + 8*(r>>2) + 4*hi (+32 for oc1)
    float inv = 1.f / lsum;
    #pragma unroll
    for (int dh = 0; dh < 2; ++dh)
      #pragma unroll
      for (int g = 0; g < 4; ++g) {
        ushort4 sv;
        float v0 = (dh ? oc1[4 * g + 0] : oc0[4 * g + 0]) * inv;
        float v1 = (dh ? oc1[4 * g + 1] : oc0[4 * g + 1]) * inv;
        float v2 = (dh ? oc1[4 * g + 2] : oc0[4 * g + 2]) * inv;
        float v3 = (dh ? oc1[4 * g + 3] : oc0[4 * g + 3]) * inv;
        sv.x = f2b(v0); sv.y = f2b(v1); sv.z = f2b(v2); sv.w = f2b(v3);
        *(ushort4*)&Cx[qrow * CD + h * 64 + dh * 32 + 8 * g + 4 * hi] = sv;
      }
  }
}

// ---------------- launch ----------------
extern "C" void kernel_launch(void* const* d_in, const int* in_sizes, int n_in,
                              void* d_out, int out_size, void* d_ws, size_t ws_size,
                              hipStream_t stream) {
  const float* x  = (const float*)d_in[0];
  const float* Wq = (const float*)d_in[1];
  const float* Wk = (const float*)d_in[2];
  const float* Wv = (const float*)d_in[3];
  const float* Wo = (const float*)d_in[4];
  const float* bo = (const float*)d_in[5];
  float* out = (float*)d_out;

  char* W = (char*)d_ws;
  unsigned short* xb  = (unsigned short*)(W);                 // 16 MB
  unsigned short* WqT = (unsigned short*)(W + (16u << 20));   // 2 MB (contig with Wk,Wv)
  unsigned short* WkT = (unsigned short*)(W + (18u << 20));
  unsigned short* WvT = (unsigned short*)(W + (20u << 20));
  unsigned short* WoT = (unsigned short*)(W + (22u << 20));
  unsigned short* Qm  = (unsigned short*)(W + (24u << 20));   // (B,T,C)
  unsigned short* Km  = (unsigned short*)(W + (40u << 20));   // (B,T,C)
  unsigned short* Vt  = (unsigned short*)(W + (56u << 20));   // (B,H,D,T)
  unsigned short* Cx  = (unsigned short*)(W + (72u << 20));   // (B,T,C)

  hipLaunchKernelGGL(cast_x_k, dim3(4096), dim3(256), 0, stream, x, xb);
  hipLaunchKernelGGL(castT_k, dim3(32, 32, 4), dim3(256), 0, stream,
                     Wq, Wk, Wv, Wo, WqT, WkT, WvT, WoT);
  // fused QKV projection: Bt = [WqT;WkT;WvT] rows 0..3071
  hipLaunchKernelGGL((gemm_k<3>), dim3(64, 24), dim3(256), 0, stream,
                     xb, WqT, (void*)Qm, (void*)Km, (void*)Vt, (const float*)nullptr);
  hipLaunchKernelGGL(attn_k, dim3(512), dim3(256), 0, stream, Qm, Km, Vt, Cx);
  hipLaunchKernelGGL((gemm_k<2>), dim3(64, 8), dim3(256), 0, stream,
                     Cx, WoT, (void*)out, nullptr, nullptr, bo);
}